// Round 1
// baseline (1306.779 us; speedup 1.0000x reference)
//
#include <hip/hip_runtime.h>
#include <hip/hip_bf16.h>

// Sinkhorn distance, 8 batches x 2048 points x 2 dims, 50 iters, eps=0.1.
// Strategy: log2-domain scaled duals; rank-2 expansion of the cost matrix so
// the inner loop is 2 FMA + exp2 + add per element, j-side data held in VGPRs
// (32 j per lane), 8 rows reused per wave. 100 half-pass kernels + final
// pi/C/cost kernel.

#define P 2048
#define NB 8
constexpr float SCALE = 14.426950408889634f; // log2(e) / eps, eps = 0.1

typedef float vf4 __attribute__((ext_vector_type(4)));

__global__ void setup_kernel(const float* __restrict__ x, const float* __restrict__ yy,
                             float4* __restrict__ jpackY, float4* __restrict__ jpackX,
                             float4* __restrict__ rowX, float4* __restrict__ rowY,
                             float* __restrict__ u, float* __restrict__ v,
                             float* __restrict__ partial) {
    const int n = blockIdx.x;
    const int t = threadIdx.x;
    __shared__ float redx[256], redy[256];
    float xm0[8], xm1[8], ym0[8], ym1[8];
    float sx = 0.f, sy = 0.f;
    #pragma unroll
    for (int k = 0; k < 8; ++k) {
        int p = t + 256 * k;
        size_t base = ((size_t)n * P + p) * 2;
        float a0 = x[base + 0];
        float a1 = x[base + 1];
        float b0 = yy[base + 0];
        float b1 = yy[base + 1];
        // mask = (x != -1); applied to BOTH x and y (per reference)
        float m0 = (a0 != -1.0f) ? 1.0f : 0.0f;
        float m1 = (a1 != -1.0f) ? 1.0f : 0.0f;
        a0 *= m0; a1 *= m1; b0 *= m0; b1 *= m1;
        xm0[k] = a0; xm1[k] = a1; ym0[k] = b0; ym1[k] = b1;
        sx = fmaf(a1, a1, sx);
        sy = fmaf(b1, b1, sy);
    }
    redx[t] = sx; redy[t] = sy;
    __syncthreads();
    for (int off = 128; off > 0; off >>= 1) {
        if (t < off) { redx[t] += redx[t + off]; redy[t] += redy[t + off]; }
        __syncthreads();
    }
    const float inv_sx = 1.0f / redx[0];
    const float inv_sy = 1.0f / redy[0];
    #pragma unroll
    for (int k = 0; k < 8; ++k) {
        int p = t + 256 * k;
        float a0 = xm0[k], a1 = xm1[k], b0 = ym0[k], b1 = ym1[k];
        float qx = fmaf(a0, a0, a1 * a1);
        float qy = fmaf(b0, b0, b1 * b1);
        float mu = a1 * a1 * inv_sx;
        float nu = b1 * b1 * inv_sy;
        // B = log2(marginal + 1e-8) + s*|pt|^2  (the s*q term cancels the
        // row-constant we dropped from the exponent)
        float Bmu = __builtin_amdgcn_logf(mu + 1e-8f) + SCALE * qx;
        float Bnu = __builtin_amdgcn_logf(nu + 1e-8f) + SCALE * qy;
        size_t idx = (size_t)n * P + p;
        rowX[idx] = make_float4(a0, a1, Bmu, 0.f);
        rowY[idx] = make_float4(b0, b1, Bnu, 0.f);
        jpackX[idx] = make_float4(2.f * SCALE * a0, 2.f * SCALE * a1, SCALE * qx, 0.f);
        jpackY[idx] = make_float4(2.f * SCALE * b0, 2.f * SCALE * b1, SCALE * qy, 0.f);
        u[idx] = 0.f;
        v[idx] = 0.f;
    }
    if (n == 0) { partial[t] = 0.f; partial[t + 256] = 0.f; }
}

// One half Sinkhorn iteration (generic over direction):
//   out_i = B_i - log2( sum_j 2^( V_j + Y0_j*x0_i + Y1_j*x1_i ) )
// where V_j = dual_j - Qj, jpack = {Y0, Y1, Qj, -}, rowdat = {x0, x1, B, -}.
// Grid: 512 blocks x 256 threads; batch = blk&7; each wave holds all 2048
// j-entries in registers (32/lane) and processes 8 rows.
__global__ __launch_bounds__(256, 2) void halfpass_kernel(
        const float4* __restrict__ jpack, const float* __restrict__ jdual,
        const float4* __restrict__ rowdat, float* __restrict__ outdual) {
    const int blk = blockIdx.x;
    const int batch = blk & 7;
    const int blkin = blk >> 3;               // 0..63
    const int lane = threadIdx.x & 63;
    const int wave = threadIdx.x >> 6;        // 0..3

    const float4* jp = jpack + (size_t)batch * P;
    const float* jd = jdual + (size_t)batch * P;

    float Y0[32], Y1[32], V[32];
    #pragma unroll
    for (int k = 0; k < 32; ++k) {
        int j = lane + 64 * k;
        float4 q = jp[j];
        float dv = jd[j];
        Y0[k] = q.x;
        Y1[k] = q.y;
        V[k] = dv - q.z;
    }

    const int rowbase = blkin * 32 + wave * 8;
    const float4* rd = rowdat + (size_t)batch * P;
    float* outp = outdual + (size_t)batch * P;

    for (int r = 0; r < 8; ++r) {
        const int i = rowbase + r;
        float4 rv = rd[i];                    // wave-uniform -> scalar load
        const float x0 = rv.x, x1 = rv.y, B = rv.z;
        float a0 = 0.f, a1 = 0.f, a2 = 0.f, a3 = 0.f;
        #pragma unroll
        for (int k = 0; k < 32; k += 4) {
            a0 += __builtin_amdgcn_exp2f(fmaf(Y1[k + 0], x1, fmaf(Y0[k + 0], x0, V[k + 0])));
            a1 += __builtin_amdgcn_exp2f(fmaf(Y1[k + 1], x1, fmaf(Y0[k + 1], x0, V[k + 1])));
            a2 += __builtin_amdgcn_exp2f(fmaf(Y1[k + 2], x1, fmaf(Y0[k + 2], x0, V[k + 2])));
            a3 += __builtin_amdgcn_exp2f(fmaf(Y1[k + 3], x1, fmaf(Y0[k + 3], x0, V[k + 3])));
        }
        float acc = (a0 + a1) + (a2 + a3);
        #pragma unroll
        for (int m = 1; m < 64; m <<= 1) acc += __shfl_xor(acc, m, 64);
        if (lane == 0) outp[i] = B - __builtin_amdgcn_logf(acc);
    }
}

// Final: pi = 2^(u~_i + v~_j - s*C_ij), C, and cost partials.
// Grid: 16384 blocks (batch = blk&7, row i = blk>>3) x 256 threads; each
// thread handles 8 j's as two float4 groups.
__global__ void final_kernel(const float4* __restrict__ rowX, const float4* __restrict__ rowY,
                             const float* __restrict__ u, const float* __restrict__ v,
                             float* __restrict__ out, float* __restrict__ partial) {
    const int blk = blockIdx.x;
    const int batch = blk & 7;
    const int i = blk >> 3;
    const int t = threadIdx.x;

    const float4 rx = rowX[(size_t)batch * P + i];
    const float ui = u[(size_t)batch * P + i];
    const float x0 = rx.x, x1 = rx.y;

    float* pi_out = out + 8 + (size_t)batch * P * P + (size_t)i * P;
    float* C_out = pi_out + (size_t)NB * P * P;
    const float4* ry = rowY + (size_t)batch * P;
    const float* vv = v + (size_t)batch * P;

    float costacc = 0.f;
    #pragma unroll
    for (int c = 0; c < 2; ++c) {
        const int j0 = c * 1024 + t * 4;
        vf4 vj = *(const vf4*)(vv + j0);
        vf4 Cv, Pv;
        #pragma unroll
        for (int e = 0; e < 4; ++e) {
            float4 q = ry[j0 + e];
            float dx = x0 - q.x;
            float dy = x1 - q.y;
            float Cj = fmaf(dy, dy, dx * dx);
            float pj = __builtin_amdgcn_exp2f(fmaf(Cj, -SCALE, ui + vj[e]));
            Cv[e] = Cj;
            Pv[e] = pj;
            costacc = fmaf(pj, Cj, costacc);
        }
        __builtin_nontemporal_store(Pv, (vf4*)(pi_out + j0));
        __builtin_nontemporal_store(Cv, (vf4*)(C_out + j0));
    }

    #pragma unroll
    for (int m = 1; m < 64; m <<= 1) costacc += __shfl_xor(costacc, m, 64);
    __shared__ float sred[4];
    const int wave = t >> 6, lane = t & 63;
    if (lane == 0) sred[wave] = costacc;
    __syncthreads();
    if (t == 0) {
        float s = sred[0] + sred[1] + sred[2] + sred[3];
        atomicAdd(&partial[batch * 64 + (i & 63)], s);
    }
}

__global__ void costreduce_kernel(const float* __restrict__ partial, float* __restrict__ out) {
    const int t = threadIdx.x; // 512 threads: wave w reduces batch w's 64 slots
    float val = partial[t];
    #pragma unroll
    for (int m = 1; m < 64; m <<= 1) val += __shfl_xor(val, m, 64);
    if ((t & 63) == 0) out[t >> 6] = val;
}

extern "C" void kernel_launch(void* const* d_in, const int* in_sizes, int n_in,
                              void* d_out, int out_size, void* d_ws, size_t ws_size,
                              hipStream_t stream) {
    const float* x = (const float*)d_in[0];
    const float* y = (const float*)d_in[1];
    float* out = (float*)d_out;
    float* ws = (float*)d_ws;

    // ws layout (floats): jpackY[16384 f4] | jpackX[16384 f4] | rowX | rowY |
    //                     u[16384] | v[16384] | partial[512]   (~1.13 MB)
    float4* jpackY = (float4*)ws;
    float4* jpackX = (float4*)(ws + 65536);
    float4* rowX = (float4*)(ws + 131072);
    float4* rowY = (float4*)(ws + 196608);
    float* u = ws + 262144;
    float* v = ws + 262144 + 16384;
    float* partial = ws + 262144 + 32768;

    setup_kernel<<<8, 256, 0, stream>>>(x, y, jpackY, jpackX, rowX, rowY, u, v, partial);
    for (int it = 0; it < 50; ++it) {
        // u-update: reduce over j (y side in registers)
        halfpass_kernel<<<512, 256, 0, stream>>>(jpackY, v, rowX, u);
        // v-update: reduce over i (x side in registers)
        halfpass_kernel<<<512, 256, 0, stream>>>(jpackX, u, rowY, v);
    }
    final_kernel<<<16384, 256, 0, stream>>>(rowX, rowY, u, v, out, partial);
    costreduce_kernel<<<1, 512, 0, stream>>>(partial, out);
}